// Round 6
// baseline (234.158 us; speedup 1.0000x reference)
//
#include <hip/hip_runtime.h>

// Newton-Schulz batched inverse, 1024 x (128x128) fp32.
// R12: R11 with the register cap actually lifted. R9-R11 all allocated 64
// VGPRs and spilled wfrag (~250MB scratch traffic in R11). Diagnosis: the
// second __launch_bounds__ arg may be read with CUDA semantics (min BLOCKS
// per CU) -> (1024,4) demanded 64 waves/CU -> clamped to the 64-reg budget.
// (1024,1) is the loosest request under EITHER interpretation (16 waves/CU
// -> 128-reg cap, or 1 wave/EU -> 256+). Live set ~88 regs -> spill-free.
//  - wfrag (bf16(W) row fragments) in registers; wrm buffer gone
//    (R10/R11 evidence: this is what cut bank conflicts 1.64e7 -> 3.5e6)
//  - SROW=132 padded fp32 stage (init-read conflicts)
//  - norms max-reduce unrolled x4 (max is exactly associative -> same bits)
// All changes allocation/order only -> bit-identical output (9.155e-5).
// 1024 thr / 16 waves / 1 block/CU; 3 barriers/iter; LDS 130KB.

#define NN 128

typedef __attribute__((ext_vector_type(8))) short bf16x8;
typedef __attribute__((ext_vector_type(16))) float f32x16;
typedef __attribute__((ext_vector_type(4))) float f32x4;
typedef __attribute__((ext_vector_type(4))) unsigned short us4;

// LDS layout (bytes):
#define XRM_OFF   0        // X row-major bf16                 32768
#define XCM_OFF   32768    // X col-major bf16                 32768
#define SCR_OFF   65536    // T col-major bf16                 32768
#define STAGE_OFF 65536    // fp32 W stage [65536,133120); dead before scr use
#define RED_OFF   0        // 256 floats in xrm region during phase 0 only
#define LDS_BYTES 133120
#define SROW 132           // stage row pitch in floats (528B = 16B mod 128B)

__device__ __forceinline__ unsigned short f2bf(float f) {
  unsigned u = __float_as_uint(f);
  return (unsigned short)((u + 0x7FFFu + ((u >> 16) & 1u)) >> 16);  // RNE
}
__device__ __forceinline__ float bf2f(unsigned short h) {
  return __uint_as_float(((unsigned)h) << 16);
}
__device__ __forceinline__ f32x16 zero16() {
  f32x16 z;
#pragma unroll
  for (int i = 0; i < 16; ++i) z[i] = 0.0f;
  return z;
}
// XOR swizzle in a [R][128] bf16 buffer: 8-elem granule g -> g ^ (R&15).
__device__ __forceinline__ int swz8(int R, int k0) {  // k0 % 8 == 0
  return R * 128 + (((k0 >> 3) ^ (R & 15)) << 3);
}
__device__ __forceinline__ int swz4(int R, int c0) {  // c0 % 4 == 0
  return R * 128 + ((((c0 >> 3) ^ (R & 15)) << 3) | (c0 & 7));
}
__device__ __forceinline__ int swz1(int R, int c) {
  return R * 128 + ((((c >> 3) ^ (R & 15)) << 3) | (c & 7));
}

__global__ void __launch_bounds__(1024, 1)
ns_inverse_kernel(const float* __restrict__ Wglob, const int* __restrict__ nIt,
                  float* __restrict__ outglob) {
  extern __shared__ char lds[];
  unsigned short* xrm = (unsigned short*)(lds + XRM_OFF);
  unsigned short* xcm = (unsigned short*)(lds + XCM_OFF);
  unsigned short* scr = (unsigned short*)(lds + SCR_OFF);
  float* stage = (float*)(lds + STAGE_OFF);
  float* red   = (float*)(lds + RED_OFF);

  const int b = blockIdx.x;
  const float* Wg = Wglob + (size_t)b * (NN * NN);
  float* outg = outglob + (size_t)b * (NN * NN);
  const int t = threadIdx.x;      // 0..1023
  const int lane = t & 63;
  const int wv = t >> 6;          // 0..15
  const int l31 = lane & 31;
  const int half = lane >> 5;
  const int s = wv & 3;           // strip: W rows (mm1 A) / X' rows (mm2 B, epi)
  const int v = wv >> 2;          // band: T cols / X' cols (mm2 A, epi)
  const int niters = nIt[0];

  // ---- phase 0: stage W fp32 into padded-pitch LDS (only global read) ----
  {
    const f32x4* src = (const f32x4*)Wg;
#pragma unroll
    for (int i = 0; i < 4; ++i) {
      int idx = t + 1024 * i;         // f32x4 index, 4096 total
      int r = idx >> 5, cp = idx & 31;
      f32x4 val = src[idx];
      *(f32x4*)(stage + r * SROW + 4 * cp) = val;
    }
  }
  __syncthreads();

  // ---- norms (red lives in xrm region; xrm filled later) ----
  if (t < 128) {            // row sums (rotated start)
    float ssum = 0.f;
    for (int jj = 0; jj < NN; ++jj) { int j = (jj + t) & 127; ssum += fabsf(stage[t * SROW + j]); }
    red[t] = ssum;
  } else if (t < 256) {     // col sums
    int c = t - 128;
    float ssum = 0.f;
    for (int i = 0; i < NN; ++i) ssum += fabsf(stage[i * SROW + c]);
    red[128 + c] = ssum;
  }
  __syncthreads();
  // max is exactly associative: 4 independent chains, then combine (same bits)
  float na0 = 0.f, na1 = 0.f, na2 = 0.f, na3 = 0.f;
  float nb0 = 0.f, nb1 = 0.f, nb2 = 0.f, nb3 = 0.f;
  for (int i = 0; i < 128; i += 4) {   // broadcast reads (same addr all lanes)
    na0 = fmaxf(na0, red[i]);       na1 = fmaxf(na1, red[i + 1]);
    na2 = fmaxf(na2, red[i + 2]);   na3 = fmaxf(na3, red[i + 3]);
    nb0 = fmaxf(nb0, red[128 + i]);     nb1 = fmaxf(nb1, red[129 + i]);
    nb2 = fmaxf(nb2, red[130 + i]);     nb3 = fmaxf(nb3, red[131 + i]);
  }
  const float ninf = fmaxf(fmaxf(na0, na1), fmaxf(na2, na3));
  const float n1   = fmaxf(fmaxf(nb0, nb1), fmaxf(nb2, nb3));
  const float scale = 1.0f / (n1 * ninf);
  __syncthreads();   // everyone has scale; red region may be overwritten now

  // ---- W row fragments to registers (bf16(W), identical bits to R6 wrm) ----
  const int pX = 32 * s + l31;    // lane-owned W row / X/X' row
  bf16x8 wfrag[8];
#pragma unroll
  for (int ks = 0; ks < 8; ++ks) {
    const float* src = stage + pX * SROW + 16 * ks + 8 * half;
    f32x4 f0 = *(const f32x4*)(src);
    f32x4 f1 = *(const f32x4*)(src + 4);
    bf16x8 wb;
#pragma unroll
    for (int e = 0; e < 4; ++e) {
      wb[e]     = (short)f2bf(f0[e]);
      wb[4 + e] = (short)f2bf(f1[e]);
    }
    wfrag[ks] = wb;
  }

  // ---- fills from stage ----
  // xcm row r = X0 col r = W row r * scale
  {
    const int r = t >> 3;
    const int c0 = (t & 7) * 16;
#pragma unroll
    for (int h = 0; h < 4; ++h) {
      f32x4 a = *(const f32x4*)(stage + r * SROW + c0 + 4 * h);
      us4 hx;
#pragma unroll
      for (int i = 0; i < 4; ++i) hx[i] = f2bf(a[i] * scale);
      *(us4*)(xcm + swz4(r, c0 + 4 * h)) = hx;
    }
  }
  // xrm row r = X0 row r = W col r * scale (LDS transpose from stage)
  {
    const int r = t & 127;
    const int kc = (t >> 7) * 16;
#pragma unroll
    for (int j4 = 0; j4 < 4; ++j4) {
      int c0 = kc + 4 * j4;
      us4 h4;
#pragma unroll
      for (int i = 0; i < 4; ++i) h4[i] = f2bf(stage[(c0 + i) * SROW + r] * scale);
      *(us4*)(xrm + swz4(r, c0)) = h4;
    }
  }
  __syncthreads();   // stage dead from here; scr region free

  // ---------------- iterations: X' = 2X - X(WX) ----------------
  const int rv = 32 * v + l31;    // lane-owned xcm/scr row (= T col = X' col band)
  for (int it = 0; it < niters; ++it) {
    const bool last = (it == niters - 1);

    // ---- mm1: T tile rows [32s..), cols [32v..): A=wfrag (regs), B=xcm ----
    {
      f32x16 tt = zero16();
#pragma unroll
      for (int ks = 0; ks < 8; ++ks) {
        int k0 = ks * 16 + half * 8;
        bf16x8 bv = *(const bf16x8*)(xcm + swz8(rv, k0));
        tt = __builtin_amdgcn_mfma_f32_32x32x16_bf16(wfrag[ks], bv, tt, 0, 0, 0);
      }
      // write T tile into scr (T col-major): scr row rv, cols = T rows strip s
#pragma unroll
      for (int q = 0; q < 4; ++q) {
        us4 h4;
#pragma unroll
        for (int i = 0; i < 4; ++i) h4[i] = f2bf(tt[4 * q + i]);
        *(us4*)(scr + swz4(rv, 32 * s + 8 * q + 4 * half)) = h4;
      }
    }
    __syncthreads();   // B1: full T assembled

    // ---- mm2: (X@T)^T tile rows [32v..) (X' cols), cols [32s..) (X' rows) ----
    f32x16 acc = zero16();
#pragma unroll
    for (int ks = 0; ks < 8; ++ks) {
      int k0 = ks * 16 + half * 8;
      bf16x8 av = *(const bf16x8*)(scr + swz8(rv, k0));   // T col-major row
      bf16x8 bv = *(const bf16x8*)(xrm + swz8(pX, k0));   // old X row
      acc = __builtin_amdgcn_mfma_f32_32x32x16_bf16(av, bv, acc, 0, 0, 0);
    }
    __syncthreads();   // B2: all scr + xrm reads complete before overwrite

    // ---- epilogue: X'[pX][32v + m] = 2X - (X@T) ----
#pragma unroll
    for (int q = 0; q < 4; ++q) {
      int c0m = 32 * v + 8 * q + 4 * half;
      int offr = swz4(pX, c0m);
      us4 xh4 = *(const us4*)(xrm + offr);
      f32x4 vv;
#pragma unroll
      for (int i = 0; i < 4; ++i)
        vv[i] = 2.0f * bf2f(xh4[i]) - acc[4 * q + i];
      if (last) {
        *(f32x4*)(outg + pX * NN + c0m) = vv;
      } else {
        us4 h4;
#pragma unroll
        for (int i = 0; i < 4; ++i) {
          unsigned short hh = f2bf(vv[i]);
          h4[i] = hh;
          xcm[swz1(c0m + i, pX)] = hh;     // X' col-major
        }
        *(us4*)(xrm + offr) = h4;          // X' row-major
      }
    }
    __syncthreads();   // B3: X' committed before next mm1
  }
}

extern "C" void kernel_launch(void* const* d_in, const int* in_sizes, int n_in,
                              void* d_out, int out_size, void* d_ws, size_t ws_size,
                              hipStream_t stream) {
  const float* W = (const float*)d_in[0];
  const int* nIt = (const int*)d_in[1];
  float* out = (float*)d_out;
  const int nmat = in_sizes[0] / (NN * NN);   // 1024

  hipFuncSetAttribute((const void*)ns_inverse_kernel,
                      hipFuncAttributeMaxDynamicSharedMemorySize, LDS_BYTES);
  ns_inverse_kernel<<<nmat, 1024, LDS_BYTES, stream>>>(W, nIt, out);
}

// Round 7
// 230.162 us; speedup vs baseline: 1.0174x; 1.0174x over previous
//
#include <hip/hip_runtime.h>

// Newton-Schulz batched inverse, 1024 x (128x128) fp32.
// R13: R12 + amdgpu_waves_per_eu(4,4). R9-R12 all allocated 64 VGPRs and
// spilled wfrag (~260MB scratch traffic): every prior knob set a MINIMUM
// occupancy (launch_bounds 2nd arg = min waves/EU; single-arg waves_per_eu
// = min only), which 64 regs trivially satisfies -> occupancy-greedy
// allocator kept the 8-waves/EU 64-reg budget (it can't see our dynamic
// 133KB LDS already caps us at 4 waves/EU). The two-arg form sets MAX=4
// -> 512/4 = 128-reg budget; live set ~88 -> spill-free, zero occupancy
// cost (we physically run exactly 4 waves/EU).
//  - wfrag (bf16(W) row fragments) in registers; wrm buffer gone
//  - SROW=132 padded fp32 stage; 4-bit XOR swizzle
// All changes allocation-only -> bit-identical output (9.155e-5).
// 1024 thr / 16 waves / 1 block/CU; 3 barriers/iter; LDS 130KB.

#define NN 128

typedef __attribute__((ext_vector_type(8))) short bf16x8;
typedef __attribute__((ext_vector_type(16))) float f32x16;
typedef __attribute__((ext_vector_type(4))) float f32x4;
typedef __attribute__((ext_vector_type(4))) unsigned short us4;

// LDS layout (bytes):
#define XRM_OFF   0        // X row-major bf16                 32768
#define XCM_OFF   32768    // X col-major bf16                 32768
#define SCR_OFF   65536    // T col-major bf16                 32768
#define STAGE_OFF 65536    // fp32 W stage [65536,133120); dead before scr use
#define RED_OFF   0        // 256 floats in xrm region during phase 0 only
#define LDS_BYTES 133120
#define SROW 132           // stage row pitch in floats (528B = 16B mod 128B)

__device__ __forceinline__ unsigned short f2bf(float f) {
  unsigned u = __float_as_uint(f);
  return (unsigned short)((u + 0x7FFFu + ((u >> 16) & 1u)) >> 16);  // RNE
}
__device__ __forceinline__ float bf2f(unsigned short h) {
  return __uint_as_float(((unsigned)h) << 16);
}
__device__ __forceinline__ f32x16 zero16() {
  f32x16 z;
#pragma unroll
  for (int i = 0; i < 16; ++i) z[i] = 0.0f;
  return z;
}
// XOR swizzle in a [R][128] bf16 buffer: 8-elem granule g -> g ^ (R&15).
__device__ __forceinline__ int swz8(int R, int k0) {  // k0 % 8 == 0
  return R * 128 + (((k0 >> 3) ^ (R & 15)) << 3);
}
__device__ __forceinline__ int swz4(int R, int c0) {  // c0 % 4 == 0
  return R * 128 + ((((c0 >> 3) ^ (R & 15)) << 3) | (c0 & 7));
}
__device__ __forceinline__ int swz1(int R, int c) {
  return R * 128 + ((((c >> 3) ^ (R & 15)) << 3) | (c & 7));
}

__global__ void __launch_bounds__(1024)
__attribute__((amdgpu_waves_per_eu(4, 4)))
ns_inverse_kernel(const float* __restrict__ Wglob, const int* __restrict__ nIt,
                  float* __restrict__ outglob) {
  extern __shared__ char lds[];
  unsigned short* xrm = (unsigned short*)(lds + XRM_OFF);
  unsigned short* xcm = (unsigned short*)(lds + XCM_OFF);
  unsigned short* scr = (unsigned short*)(lds + SCR_OFF);
  float* stage = (float*)(lds + STAGE_OFF);
  float* red   = (float*)(lds + RED_OFF);

  const int b = blockIdx.x;
  const float* Wg = Wglob + (size_t)b * (NN * NN);
  float* outg = outglob + (size_t)b * (NN * NN);
  const int t = threadIdx.x;      // 0..1023
  const int lane = t & 63;
  const int wv = t >> 6;          // 0..15
  const int l31 = lane & 31;
  const int half = lane >> 5;
  const int s = wv & 3;           // strip: W rows (mm1 A) / X' rows (mm2 B, epi)
  const int v = wv >> 2;          // band: T cols / X' cols (mm2 A, epi)
  const int niters = nIt[0];

  // ---- phase 0: stage W fp32 into padded-pitch LDS (only global read) ----
  {
    const f32x4* src = (const f32x4*)Wg;
#pragma unroll
    for (int i = 0; i < 4; ++i) {
      int idx = t + 1024 * i;         // f32x4 index, 4096 total
      int r = idx >> 5, cp = idx & 31;
      f32x4 val = src[idx];
      *(f32x4*)(stage + r * SROW + 4 * cp) = val;
    }
  }
  __syncthreads();

  // ---- norms (red lives in xrm region; xrm filled later) ----
  if (t < 128) {            // row sums (rotated start)
    float ssum = 0.f;
    for (int jj = 0; jj < NN; ++jj) { int j = (jj + t) & 127; ssum += fabsf(stage[t * SROW + j]); }
    red[t] = ssum;
  } else if (t < 256) {     // col sums
    int c = t - 128;
    float ssum = 0.f;
    for (int i = 0; i < NN; ++i) ssum += fabsf(stage[i * SROW + c]);
    red[128 + c] = ssum;
  }
  __syncthreads();
  // max is exactly associative: 4 independent chains, then combine (same bits)
  float na0 = 0.f, na1 = 0.f, na2 = 0.f, na3 = 0.f;
  float nb0 = 0.f, nb1 = 0.f, nb2 = 0.f, nb3 = 0.f;
  for (int i = 0; i < 128; i += 4) {   // broadcast reads (same addr all lanes)
    na0 = fmaxf(na0, red[i]);       na1 = fmaxf(na1, red[i + 1]);
    na2 = fmaxf(na2, red[i + 2]);   na3 = fmaxf(na3, red[i + 3]);
    nb0 = fmaxf(nb0, red[128 + i]);     nb1 = fmaxf(nb1, red[129 + i]);
    nb2 = fmaxf(nb2, red[130 + i]);     nb3 = fmaxf(nb3, red[131 + i]);
  }
  const float ninf = fmaxf(fmaxf(na0, na1), fmaxf(na2, na3));
  const float n1   = fmaxf(fmaxf(nb0, nb1), fmaxf(nb2, nb3));
  const float scale = 1.0f / (n1 * ninf);
  __syncthreads();   // everyone has scale; red region may be overwritten now

  // ---- W row fragments to registers (bf16(W), identical bits to R6 wrm) ----
  const int pX = 32 * s + l31;    // lane-owned W row / X/X' row
  bf16x8 wfrag[8];
#pragma unroll
  for (int ks = 0; ks < 8; ++ks) {
    const float* src = stage + pX * SROW + 16 * ks + 8 * half;
    f32x4 f0 = *(const f32x4*)(src);
    f32x4 f1 = *(const f32x4*)(src + 4);
    bf16x8 wb;
#pragma unroll
    for (int e = 0; e < 4; ++e) {
      wb[e]     = (short)f2bf(f0[e]);
      wb[4 + e] = (short)f2bf(f1[e]);
    }
    wfrag[ks] = wb;
  }

  // ---- fills from stage ----
  // xcm row r = X0 col r = W row r * scale
  {
    const int r = t >> 3;
    const int c0 = (t & 7) * 16;
#pragma unroll
    for (int h = 0; h < 4; ++h) {
      f32x4 a = *(const f32x4*)(stage + r * SROW + c0 + 4 * h);
      us4 hx;
#pragma unroll
      for (int i = 0; i < 4; ++i) hx[i] = f2bf(a[i] * scale);
      *(us4*)(xcm + swz4(r, c0 + 4 * h)) = hx;
    }
  }
  // xrm row r = X0 row r = W col r * scale (LDS transpose from stage)
  {
    const int r = t & 127;
    const int kc = (t >> 7) * 16;
#pragma unroll
    for (int j4 = 0; j4 < 4; ++j4) {
      int c0 = kc + 4 * j4;
      us4 h4;
#pragma unroll
      for (int i = 0; i < 4; ++i) h4[i] = f2bf(stage[(c0 + i) * SROW + r] * scale);
      *(us4*)(xrm + swz4(r, c0)) = h4;
    }
  }
  __syncthreads();   // stage dead from here; scr region free

  // ---------------- iterations: X' = 2X - X(WX) ----------------
  const int rv = 32 * v + l31;    // lane-owned xcm/scr row (= T col = X' col band)
  for (int it = 0; it < niters; ++it) {
    const bool last = (it == niters - 1);

    // ---- mm1: T tile rows [32s..), cols [32v..): A=wfrag (regs), B=xcm ----
    {
      f32x16 tt = zero16();
#pragma unroll
      for (int ks = 0; ks < 8; ++ks) {
        int k0 = ks * 16 + half * 8;
        bf16x8 bv = *(const bf16x8*)(xcm + swz8(rv, k0));
        tt = __builtin_amdgcn_mfma_f32_32x32x16_bf16(wfrag[ks], bv, tt, 0, 0, 0);
      }
      // write T tile into scr (T col-major): scr row rv, cols = T rows strip s
#pragma unroll
      for (int q = 0; q < 4; ++q) {
        us4 h4;
#pragma unroll
        for (int i = 0; i < 4; ++i) h4[i] = f2bf(tt[4 * q + i]);
        *(us4*)(scr + swz4(rv, 32 * s + 8 * q + 4 * half)) = h4;
      }
    }
    __syncthreads();   // B1: full T assembled

    // ---- mm2: (X@T)^T tile rows [32v..) (X' cols), cols [32s..) (X' rows) ----
    f32x16 acc = zero16();
#pragma unroll
    for (int ks = 0; ks < 8; ++ks) {
      int k0 = ks * 16 + half * 8;
      bf16x8 av = *(const bf16x8*)(scr + swz8(rv, k0));   // T col-major row
      bf16x8 bv = *(const bf16x8*)(xrm + swz8(pX, k0));   // old X row
      acc = __builtin_amdgcn_mfma_f32_32x32x16_bf16(av, bv, acc, 0, 0, 0);
    }
    __syncthreads();   // B2: all scr + xrm reads complete before overwrite

    // ---- epilogue: X'[pX][32v + m] = 2X - (X@T) ----
#pragma unroll
    for (int q = 0; q < 4; ++q) {
      int c0m = 32 * v + 8 * q + 4 * half;
      int offr = swz4(pX, c0m);
      us4 xh4 = *(const us4*)(xrm + offr);
      f32x4 vv;
#pragma unroll
      for (int i = 0; i < 4; ++i)
        vv[i] = 2.0f * bf2f(xh4[i]) - acc[4 * q + i];
      if (last) {
        *(f32x4*)(outg + pX * NN + c0m) = vv;
      } else {
        us4 h4;
#pragma unroll
        for (int i = 0; i < 4; ++i) {
          unsigned short hh = f2bf(vv[i]);
          h4[i] = hh;
          xcm[swz1(c0m + i, pX)] = hh;     // X' col-major
        }
        *(us4*)(xrm + offr) = h4;          // X' row-major
      }
    }
    __syncthreads();   // B3: X' committed before next mm1
  }
}

extern "C" void kernel_launch(void* const* d_in, const int* in_sizes, int n_in,
                              void* d_out, int out_size, void* d_ws, size_t ws_size,
                              hipStream_t stream) {
  const float* W = (const float*)d_in[0];
  const int* nIt = (const int*)d_in[1];
  float* out = (float*)d_out;
  const int nmat = in_sizes[0] / (NN * NN);   // 1024

  hipFuncSetAttribute((const void*)ns_inverse_kernel,
                      hipFuncAttributeMaxDynamicSharedMemorySize, LDS_BYTES);
  ns_inverse_kernel<<<nmat, 1024, LDS_BYTES, stream>>>(W, nIt, out);
}

// Round 8
// 185.609 us; speedup vs baseline: 1.2616x; 1.2400x over previous
//
#include <hip/hip_runtime.h>

// Newton-Schulz batched inverse, 1024 x (128x128) fp32.
// R14: 512-thread re-tiling of the verified R6 algorithm (bit-identical
// numerics). R9-R13 showed the allocator pins 64 VGPRs for 1024-thread
// blocks regardless of launch_bounds/waves_per_eu (5 data points), while
// 256/512-thread reference kernels get 164-249 VGPRs. So: 8 waves, each
// wave computes TWO output tiles (its R6 tile pair (s,v0),(s,v1)):
//  - wfrag (bf16 W rows) in regs, shared by both mm1 tiles
//    -> mm1 LDS reads halved vs R6 (no wrm buffer, no wrm reads)
//  - mm2 B-frag (xrm row pX, s-only dependent) shared by both tiles
//  - amdgpu_waves_per_eu(2,2): we physically run 2 waves/EU (1 block/CU
//    at 133KB LDS) -> 256-reg budget, zero occupancy cost
//  - SROW=132 padded fp32 stage; x4-unrolled norm max (both proven)
// Every rounding point / MFMA chain identical to R6 -> absmax 9.155e-5.

#define NN 128

typedef __attribute__((ext_vector_type(8))) short bf16x8;
typedef __attribute__((ext_vector_type(16))) float f32x16;
typedef __attribute__((ext_vector_type(4))) float f32x4;
typedef __attribute__((ext_vector_type(4))) unsigned short us4;

// LDS layout (bytes):
#define XRM_OFF   0        // X row-major bf16                 32768
#define XCM_OFF   32768    // X col-major bf16                 32768
#define SCR_OFF   65536    // T col-major bf16                 32768
#define STAGE_OFF 65536    // fp32 W stage [65536,133120); dead before scr use
#define RED_OFF   0        // 256 floats in xrm region during phase 0 only
#define LDS_BYTES 133120
#define SROW 132           // stage row pitch in floats (528B = 16B mod 128B)

__device__ __forceinline__ unsigned short f2bf(float f) {
  unsigned u = __float_as_uint(f);
  return (unsigned short)((u + 0x7FFFu + ((u >> 16) & 1u)) >> 16);  // RNE
}
__device__ __forceinline__ float bf2f(unsigned short h) {
  return __uint_as_float(((unsigned)h) << 16);
}
__device__ __forceinline__ f32x16 zero16() {
  f32x16 z;
#pragma unroll
  for (int i = 0; i < 16; ++i) z[i] = 0.0f;
  return z;
}
// XOR swizzle in a [R][128] bf16 buffer: 8-elem granule g -> g ^ (R&15).
__device__ __forceinline__ int swz8(int R, int k0) {  // k0 % 8 == 0
  return R * 128 + (((k0 >> 3) ^ (R & 15)) << 3);
}
__device__ __forceinline__ int swz4(int R, int c0) {  // c0 % 4 == 0
  return R * 128 + ((((c0 >> 3) ^ (R & 15)) << 3) | (c0 & 7));
}
__device__ __forceinline__ int swz1(int R, int c) {
  return R * 128 + ((((c >> 3) ^ (R & 15)) << 3) | (c & 7));
}

__global__ void __launch_bounds__(512)
__attribute__((amdgpu_waves_per_eu(2, 2)))
ns_inverse_kernel(const float* __restrict__ Wglob, const int* __restrict__ nIt,
                  float* __restrict__ outglob) {
  extern __shared__ char lds[];
  unsigned short* xrm = (unsigned short*)(lds + XRM_OFF);
  unsigned short* xcm = (unsigned short*)(lds + XCM_OFF);
  unsigned short* scr = (unsigned short*)(lds + SCR_OFF);
  float* stage = (float*)(lds + STAGE_OFF);
  float* red   = (float*)(lds + RED_OFF);

  const int b = blockIdx.x;
  const float* Wg = Wglob + (size_t)b * (NN * NN);
  float* outg = outglob + (size_t)b * (NN * NN);
  const int t = threadIdx.x;      // 0..511
  const int lane = t & 63;
  const int wv = t >> 6;          // 0..7
  const int l31 = lane & 31;
  const int half = lane >> 5;
  const int s = wv & 3;           // strip: W rows (mm1 A) / X' rows (mm2 B, epi)
  const int g = wv >> 2;          // band pair: tiles v0=2g, v1=2g+1
  const int v0 = 2 * g, v1 = 2 * g + 1;
  const int niters = nIt[0];

  // ---- phase 0: stage W fp32 into padded-pitch LDS (only global read) ----
  {
    const f32x4* src = (const f32x4*)Wg;
#pragma unroll
    for (int i = 0; i < 8; ++i) {
      int idx = t + 512 * i;          // f32x4 index, 4096 total
      int r = idx >> 5, cp = idx & 31;
      f32x4 val = src[idx];
      *(f32x4*)(stage + r * SROW + 4 * cp) = val;
    }
  }
  __syncthreads();

  // ---- norms (red lives in xrm region; xrm filled later) ----
  if (t < 128) {            // row sums (rotated start)
    float ssum = 0.f;
    for (int jj = 0; jj < NN; ++jj) { int j = (jj + t) & 127; ssum += fabsf(stage[t * SROW + j]); }
    red[t] = ssum;
  } else if (t < 256) {     // col sums
    int c = t - 128;
    float ssum = 0.f;
    for (int i = 0; i < NN; ++i) ssum += fabsf(stage[i * SROW + c]);
    red[128 + c] = ssum;
  }
  __syncthreads();
  // max is exactly associative: 4 independent chains, then combine (same bits)
  float na0 = 0.f, na1 = 0.f, na2 = 0.f, na3 = 0.f;
  float nb0 = 0.f, nb1 = 0.f, nb2 = 0.f, nb3 = 0.f;
  for (int i = 0; i < 128; i += 4) {   // broadcast reads (same addr all lanes)
    na0 = fmaxf(na0, red[i]);       na1 = fmaxf(na1, red[i + 1]);
    na2 = fmaxf(na2, red[i + 2]);   na3 = fmaxf(na3, red[i + 3]);
    nb0 = fmaxf(nb0, red[128 + i]);     nb1 = fmaxf(nb1, red[129 + i]);
    nb2 = fmaxf(nb2, red[130 + i]);     nb3 = fmaxf(nb3, red[131 + i]);
  }
  const float ninf = fmaxf(fmaxf(na0, na1), fmaxf(na2, na3));
  const float n1   = fmaxf(fmaxf(nb0, nb1), fmaxf(nb2, nb3));
  const float scale = 1.0f / (n1 * ninf);
  __syncthreads();   // everyone has scale; red region may be overwritten now

  // ---- W row fragments to registers (bf16(W), identical bits to R6 wrm) ----
  const int pX = 32 * s + l31;    // lane-owned W row / X/X' row
  bf16x8 wfrag[8];
#pragma unroll
  for (int ks = 0; ks < 8; ++ks) {
    const float* src = stage + pX * SROW + 16 * ks + 8 * half;
    f32x4 f0 = *(const f32x4*)(src);
    f32x4 f1 = *(const f32x4*)(src + 4);
    bf16x8 wb;
#pragma unroll
    for (int e = 0; e < 4; ++e) {
      wb[e]     = (short)f2bf(f0[e]);
      wb[4 + e] = (short)f2bf(f1[e]);
    }
    wfrag[ks] = wb;
  }

  // ---- fills from stage (512-thread split; same values/locations as R6) ----
  // xcm row r = X0 col r = W row r * scale
  {
    const int r = t >> 2;               // 0..127
    const int c0 = (t & 3) * 32;        // 32 cols per thread
#pragma unroll
    for (int h = 0; h < 8; ++h) {
      f32x4 a = *(const f32x4*)(stage + r * SROW + c0 + 4 * h);
      us4 hx;
#pragma unroll
      for (int i = 0; i < 4; ++i) hx[i] = f2bf(a[i] * scale);
      *(us4*)(xcm + swz4(r, c0 + 4 * h)) = hx;
    }
  }
  // xrm row r = X0 row r = W col r * scale (LDS transpose from stage)
  {
    const int r = t & 127;
    const int kc = (t >> 7) * 32;       // 4 groups x 32 cols
#pragma unroll
    for (int j4 = 0; j4 < 8; ++j4) {
      int c0 = kc + 4 * j4;
      us4 h4;
#pragma unroll
      for (int i = 0; i < 4; ++i) h4[i] = f2bf(stage[(c0 + i) * SROW + r] * scale);
      *(us4*)(xrm + swz4(r, c0)) = h4;
    }
  }
  __syncthreads();   // stage dead from here; scr region free

  // ---------------- iterations: X' = 2X - X(WX) ----------------
  const int rv0 = 32 * v0 + l31;   // lane-owned xcm/scr rows (T cols)
  const int rv1 = 32 * v1 + l31;
  for (int it = 0; it < niters; ++it) {
    const bool last = (it == niters - 1);

    // ---- mm1: T tiles (s,v0) and (s,v1): A=wfrag (regs), B=xcm ----
#pragma unroll
    for (int i2 = 0; i2 < 2; ++i2) {
      const int rv = i2 ? rv1 : rv0;
      f32x16 tt = zero16();
#pragma unroll
      for (int ks = 0; ks < 8; ++ks) {
        int k0 = ks * 16 + half * 8;
        bf16x8 bv = *(const bf16x8*)(xcm + swz8(rv, k0));
        tt = __builtin_amdgcn_mfma_f32_32x32x16_bf16(wfrag[ks], bv, tt, 0, 0, 0);
      }
      // write T tile into scr (T col-major): scr row rv, cols = T rows strip s
#pragma unroll
      for (int q = 0; q < 4; ++q) {
        us4 h4;
#pragma unroll
        for (int i = 0; i < 4; ++i) h4[i] = f2bf(tt[4 * q + i]);
        *(us4*)(scr + swz4(rv, 32 * s + 8 * q + 4 * half)) = h4;
      }
    }
    __syncthreads();   // B1: full T assembled

    // ---- mm2: two (X@T)^T tiles; B-frag (xrm row pX) shared ----
    f32x16 acc0 = zero16(), acc1 = zero16();
#pragma unroll
    for (int ks = 0; ks < 8; ++ks) {
      int k0 = ks * 16 + half * 8;
      bf16x8 bv = *(const bf16x8*)(xrm + swz8(pX, k0));    // old X row (shared)
      bf16x8 a0 = *(const bf16x8*)(scr + swz8(rv0, k0));   // T col-major rows
      bf16x8 a1 = *(const bf16x8*)(scr + swz8(rv1, k0));
      acc0 = __builtin_amdgcn_mfma_f32_32x32x16_bf16(a0, bv, acc0, 0, 0, 0);
      acc1 = __builtin_amdgcn_mfma_f32_32x32x16_bf16(a1, bv, acc1, 0, 0, 0);
    }
    __syncthreads();   // B2: all scr + xrm reads complete before overwrite

    // ---- epilogue: X'[pX][32v + m] = 2X - (X@T), both bands ----
#pragma unroll
    for (int i2 = 0; i2 < 2; ++i2) {
      const int vb = i2 ? v1 : v0;
#pragma unroll
      for (int q = 0; q < 4; ++q) {
        int c0m = 32 * vb + 8 * q + 4 * half;
        int offr = swz4(pX, c0m);
        us4 xh4 = *(const us4*)(xrm + offr);
        f32x4 vv;
#pragma unroll
        for (int i = 0; i < 4; ++i)
          vv[i] = 2.0f * bf2f(xh4[i]) - (i2 ? acc1[4 * q + i] : acc0[4 * q + i]);
        if (last) {
          *(f32x4*)(outg + pX * NN + c0m) = vv;
        } else {
          us4 h4;
#pragma unroll
          for (int i = 0; i < 4; ++i) {
            unsigned short hh = f2bf(vv[i]);
            h4[i] = hh;
            xcm[swz1(c0m + i, pX)] = hh;     // X' col-major
          }
          *(us4*)(xrm + offr) = h4;          // X' row-major
        }
      }
    }
    __syncthreads();   // B3: X' committed before next mm1
  }
}

extern "C" void kernel_launch(void* const* d_in, const int* in_sizes, int n_in,
                              void* d_out, int out_size, void* d_ws, size_t ws_size,
                              hipStream_t stream) {
  const float* W = (const float*)d_in[0];
  const int* nIt = (const int*)d_in[1];
  float* out = (float*)d_out;
  const int nmat = in_sizes[0] / (NN * NN);   // 1024

  hipFuncSetAttribute((const void*)ns_inverse_kernel,
                      hipFuncAttributeMaxDynamicSharedMemorySize, LDS_BYTES);
  ns_inverse_kernel<<<nmat, 512, LDS_BYTES, stream>>>(W, nIt, out);
}

// Round 9
// 176.940 us; speedup vs baseline: 1.3234x; 1.0490x over previous
//
#include <hip/hip_runtime.h>

// Newton-Schulz batched inverse, 1024 x (128x128) fp32.
// R15: R14 + wave-parallel max reduction for the norm maxima. R14's wall
// decomposition: init ~7us of 28us/block; the serial 256-iter broadcast
// max loop alone is ~2048 wave-issues ~5us/block of LDS pipe. fmax over
// non-NaN >=0 values is exactly associative+commutative -> shuffle-tree
// reduce is BIT-IDENTICAL. Everything else unchanged from R14 (VGPR=108,
// no spill, 512 thr / 8 waves, 2 tiles/wave, wfrag in regs, SROW=132).
// Output bit-identical: absmax 9.155273e-5.

#define NN 128

typedef __attribute__((ext_vector_type(8))) short bf16x8;
typedef __attribute__((ext_vector_type(16))) float f32x16;
typedef __attribute__((ext_vector_type(4))) float f32x4;
typedef __attribute__((ext_vector_type(4))) unsigned short us4;

// LDS layout (bytes):
#define XRM_OFF   0        // X row-major bf16                 32768
#define XCM_OFF   32768    // X col-major bf16                 32768
#define SCR_OFF   65536    // T col-major bf16                 32768
#define STAGE_OFF 65536    // fp32 W stage [65536,133120); dead before scr use
#define RED_OFF   0        // 256 floats in xrm region during phase 0 only
#define LDS_BYTES 133120
#define SROW 132           // stage row pitch in floats (528B = 16B mod 128B)

__device__ __forceinline__ unsigned short f2bf(float f) {
  unsigned u = __float_as_uint(f);
  return (unsigned short)((u + 0x7FFFu + ((u >> 16) & 1u)) >> 16);  // RNE
}
__device__ __forceinline__ float bf2f(unsigned short h) {
  return __uint_as_float(((unsigned)h) << 16);
}
__device__ __forceinline__ f32x16 zero16() {
  f32x16 z;
#pragma unroll
  for (int i = 0; i < 16; ++i) z[i] = 0.0f;
  return z;
}
// XOR swizzle in a [R][128] bf16 buffer: 8-elem granule g -> g ^ (R&15).
__device__ __forceinline__ int swz8(int R, int k0) {  // k0 % 8 == 0
  return R * 128 + (((k0 >> 3) ^ (R & 15)) << 3);
}
__device__ __forceinline__ int swz4(int R, int c0) {  // c0 % 4 == 0
  return R * 128 + ((((c0 >> 3) ^ (R & 15)) << 3) | (c0 & 7));
}
__device__ __forceinline__ int swz1(int R, int c) {
  return R * 128 + ((((c >> 3) ^ (R & 15)) << 3) | (c & 7));
}

__global__ void __launch_bounds__(512)
__attribute__((amdgpu_waves_per_eu(2, 2)))
ns_inverse_kernel(const float* __restrict__ Wglob, const int* __restrict__ nIt,
                  float* __restrict__ outglob) {
  extern __shared__ char lds[];
  unsigned short* xrm = (unsigned short*)(lds + XRM_OFF);
  unsigned short* xcm = (unsigned short*)(lds + XCM_OFF);
  unsigned short* scr = (unsigned short*)(lds + SCR_OFF);
  float* stage = (float*)(lds + STAGE_OFF);
  float* red   = (float*)(lds + RED_OFF);

  const int b = blockIdx.x;
  const float* Wg = Wglob + (size_t)b * (NN * NN);
  float* outg = outglob + (size_t)b * (NN * NN);
  const int t = threadIdx.x;      // 0..511
  const int lane = t & 63;
  const int wv = t >> 6;          // 0..7
  const int l31 = lane & 31;
  const int half = lane >> 5;
  const int s = wv & 3;           // strip: W rows (mm1 A) / X' rows (mm2 B, epi)
  const int g = wv >> 2;          // band pair: tiles v0=2g, v1=2g+1
  const int v0 = 2 * g, v1 = 2 * g + 1;
  const int niters = nIt[0];

  // ---- phase 0: stage W fp32 into padded-pitch LDS (only global read) ----
  {
    const f32x4* src = (const f32x4*)Wg;
#pragma unroll
    for (int i = 0; i < 8; ++i) {
      int idx = t + 512 * i;          // f32x4 index, 4096 total
      int r = idx >> 5, cp = idx & 31;
      f32x4 val = src[idx];
      *(f32x4*)(stage + r * SROW + 4 * cp) = val;
    }
  }
  __syncthreads();

  // ---- norms (red lives in xrm region; xrm filled later) ----
  if (t < 128) {            // row sums (rotated start; serial order preserved)
    float ssum = 0.f;
    for (int jj = 0; jj < NN; ++jj) { int j = (jj + t) & 127; ssum += fabsf(stage[t * SROW + j]); }
    red[t] = ssum;
  } else if (t < 256) {     // col sums (serial order preserved)
    int c = t - 128;
    float ssum = 0.f;
    for (int i = 0; i < NN; ++i) ssum += fabsf(stage[i * SROW + c]);
    red[128 + c] = ssum;
  }
  __syncthreads();
  // Wave-parallel max reduce (fmax over non-NaN >=0 is exactly associative
  // and commutative -> bit-identical to the serial scan, ~16 LDS issues
  // instead of 256 per wave).
  float mA = fmaxf(red[lane], red[lane + 64]);          // ninf over red[0..128)
  float mB = fmaxf(red[128 + lane], red[192 + lane]);   // n1 over red[128..256)
#pragma unroll
  for (int k = 32; k >= 1; k >>= 1) {
    mA = fmaxf(mA, __shfl_xor(mA, k, 64));
    mB = fmaxf(mB, __shfl_xor(mB, k, 64));
  }
  const float ninf = mA;
  const float n1 = mB;
  const float scale = 1.0f / (n1 * ninf);
  __syncthreads();   // everyone has scale; red region may be overwritten now

  // ---- W row fragments to registers (bf16(W), identical bits to R6 wrm) ----
  const int pX = 32 * s + l31;    // lane-owned W row / X/X' row
  bf16x8 wfrag[8];
#pragma unroll
  for (int ks = 0; ks < 8; ++ks) {
    const float* src = stage + pX * SROW + 16 * ks + 8 * half;
    f32x4 f0 = *(const f32x4*)(src);
    f32x4 f1 = *(const f32x4*)(src + 4);
    bf16x8 wb;
#pragma unroll
    for (int e = 0; e < 4; ++e) {
      wb[e]     = (short)f2bf(f0[e]);
      wb[4 + e] = (short)f2bf(f1[e]);
    }
    wfrag[ks] = wb;
  }

  // ---- fills from stage (same values/locations as R6/R14) ----
  // xcm row r = X0 col r = W row r * scale
  {
    const int r = t >> 2;               // 0..127
    const int c0 = (t & 3) * 32;        // 32 cols per thread
#pragma unroll
    for (int h = 0; h < 8; ++h) {
      f32x4 a = *(const f32x4*)(stage + r * SROW + c0 + 4 * h);
      us4 hx;
#pragma unroll
      for (int i = 0; i < 4; ++i) hx[i] = f2bf(a[i] * scale);
      *(us4*)(xcm + swz4(r, c0 + 4 * h)) = hx;
    }
  }
  // xrm row r = X0 row r = W col r * scale (LDS transpose from stage)
  {
    const int r = t & 127;
    const int kc = (t >> 7) * 32;       // 4 groups x 32 cols
#pragma unroll
    for (int j4 = 0; j4 < 8; ++j4) {
      int c0 = kc + 4 * j4;
      us4 h4;
#pragma unroll
      for (int i = 0; i < 4; ++i) h4[i] = f2bf(stage[(c0 + i) * SROW + r] * scale);
      *(us4*)(xrm + swz4(r, c0)) = h4;
    }
  }
  __syncthreads();   // stage dead from here; scr region free

  // ---------------- iterations: X' = 2X - X(WX) ----------------
  const int rv0 = 32 * v0 + l31;   // lane-owned xcm/scr rows (T cols)
  const int rv1 = 32 * v1 + l31;
  for (int it = 0; it < niters; ++it) {
    const bool last = (it == niters - 1);

    // ---- mm1: T tiles (s,v0) and (s,v1): A=wfrag (regs), B=xcm ----
#pragma unroll
    for (int i2 = 0; i2 < 2; ++i2) {
      const int rv = i2 ? rv1 : rv0;
      f32x16 tt = zero16();
#pragma unroll
      for (int ks = 0; ks < 8; ++ks) {
        int k0 = ks * 16 + half * 8;
        bf16x8 bv = *(const bf16x8*)(xcm + swz8(rv, k0));
        tt = __builtin_amdgcn_mfma_f32_32x32x16_bf16(wfrag[ks], bv, tt, 0, 0, 0);
      }
      // write T tile into scr (T col-major): scr row rv, cols = T rows strip s
#pragma unroll
      for (int q = 0; q < 4; ++q) {
        us4 h4;
#pragma unroll
        for (int i = 0; i < 4; ++i) h4[i] = f2bf(tt[4 * q + i]);
        *(us4*)(scr + swz4(rv, 32 * s + 8 * q + 4 * half)) = h4;
      }
    }
    __syncthreads();   // B1: full T assembled

    // ---- mm2: two (X@T)^T tiles; B-frag (xrm row pX) shared ----
    f32x16 acc0 = zero16(), acc1 = zero16();
#pragma unroll
    for (int ks = 0; ks < 8; ++ks) {
      int k0 = ks * 16 + half * 8;
      bf16x8 bv = *(const bf16x8*)(xrm + swz8(pX, k0));    // old X row (shared)
      bf16x8 a0 = *(const bf16x8*)(scr + swz8(rv0, k0));   // T col-major rows
      bf16x8 a1 = *(const bf16x8*)(scr + swz8(rv1, k0));
      acc0 = __builtin_amdgcn_mfma_f32_32x32x16_bf16(a0, bv, acc0, 0, 0, 0);
      acc1 = __builtin_amdgcn_mfma_f32_32x32x16_bf16(a1, bv, acc1, 0, 0, 0);
    }
    __syncthreads();   // B2: all scr + xrm reads complete before overwrite

    // ---- epilogue: X'[pX][32v + m] = 2X - (X@T), both bands ----
#pragma unroll
    for (int i2 = 0; i2 < 2; ++i2) {
      const int vb = i2 ? v1 : v0;
#pragma unroll
      for (int q = 0; q < 4; ++q) {
        int c0m = 32 * vb + 8 * q + 4 * half;
        int offr = swz4(pX, c0m);
        us4 xh4 = *(const us4*)(xrm + offr);
        f32x4 vv;
#pragma unroll
        for (int i = 0; i < 4; ++i)
          vv[i] = 2.0f * bf2f(xh4[i]) - (i2 ? acc1[4 * q + i] : acc0[4 * q + i]);
        if (last) {
          *(f32x4*)(outg + pX * NN + c0m) = vv;
        } else {
          us4 h4;
#pragma unroll
          for (int i = 0; i < 4; ++i) {
            unsigned short hh = f2bf(vv[i]);
            h4[i] = hh;
            xcm[swz1(c0m + i, pX)] = hh;     // X' col-major
          }
          *(us4*)(xrm + offr) = h4;          // X' row-major
        }
      }
    }
    __syncthreads();   // B3: X' committed before next mm1
  }
}

extern "C" void kernel_launch(void* const* d_in, const int* in_sizes, int n_in,
                              void* d_out, int out_size, void* d_ws, size_t ws_size,
                              hipStream_t stream) {
  const float* W = (const float*)d_in[0];
  const int* nIt = (const int*)d_in[1];
  float* out = (float*)d_out;
  const int nmat = in_sizes[0] / (NN * NN);   // 1024

  hipFuncSetAttribute((const void*)ns_inverse_kernel,
                      hipFuncAttributeMaxDynamicSharedMemorySize, LDS_BYTES);
  ns_inverse_kernel<<<nmat, 512, LDS_BYTES, stream>>>(W, nIt, out);
}